// Round 13
// baseline (284.064 us; speedup 1.0000x reference)
//
#include <hip/hip_runtime.h>
#include <hip/hip_fp16.h>

#define DEVFN __device__ __forceinline__

constexpr int N    = 100000;
constexpr int F_IN = 166;
constexpr int HID  = 128;
constexpr int E    = 1600000;

using half8 = __attribute__((ext_vector_type(8))) _Float16;
using f32x4 = __attribute__((ext_vector_type(4))) float;

// ---- workspace layout (bytes, all 16B-aligned; ends 62.1 MB as before) ----
constexpr size_t HW_OFF   = 0;            // hW [N,128] fp16      25.6 MB
constexpr size_t GOUT_OFF = 25600000;     // GAT out [N,128] fp16 25.6 MB; ALIASED by
                                          //   interm [49*40960] i32 8.03 MB during CSR build
constexpr size_t ASRC_OFF = 51200000;     // a_src [N,4] f32       1.6 MB
constexpr size_t ADST_OFF = 52800000;     // a_dst [N,4] f32       1.6 MB
constexpr size_t ROW_OFF  = 54800000;     // rowstart [N+1] i32 (ends 55,200,004)
constexpr size_t BCNT_OFF = 55200016;     // bucket counters [49] i32 (zeroed in k_prep)
constexpr size_t WPK1_OFF = 55600544;     // Win  packed fp16 frags 49,152 B
constexpr size_t WPK2_OFF = 55649696;     // Wgat packed fp16 frags 32,768 B
constexpr size_t WPK3_OFF = 55682464;     // W1   packed fp16 frags 16,384 B
constexpr size_t CSR_OFF  = 55700000;     // csr_src [E] i32       6.4 MB

constexpr int PROJ_ROWS  = 64;
constexpr int PROJ_NB    = (N + PROJ_ROWS - 1) / PROJ_ROWS;    // 1563
constexpr int MLP_NB     = (N + 63) / 64;                      // 1563
constexpr int EPB        = 1024;   // edges binned per k_proj block

constexpr int NBUCK     = 49;
constexpr int BCAP      = 40960;

DEVFN float lrelu(float e) { return e > 0.0f ? e : 0.2f * e; }

// 8 half-precision messages (float4 raw) fma'd into 2 float4 f32 accs.
DEVFN void acc8h(const float4& q, const float x, float4& a0, float4& a1)
{
    const __half2* h = (const __half2*)&q;
    a0.x = fmaf(__low2float(h[0]),  x, a0.x);
    a0.y = fmaf(__high2float(h[0]), x, a0.y);
    a0.z = fmaf(__low2float(h[1]),  x, a0.z);
    a0.w = fmaf(__high2float(h[1]), x, a0.w);
    a1.x = fmaf(__low2float(h[2]),  x, a1.x);
    a1.y = fmaf(__high2float(h[2]), x, a1.y);
    a1.z = fmaf(__low2float(h[3]),  x, a1.z);
    a1.w = fmaf(__high2float(h[3]), x, a1.w);
}

// ---------------------------------------------------------------------------
// k_prep: pack Win/Wgat/W1 into fp16 MFMA B-fragment layout + zero bcnt.
// ---------------------------------------------------------------------------
__global__ __launch_bounds__(256) void k_prep(const float* __restrict__ Win,
                                              const float* __restrict__ Wgat,
                                              const float* __restrict__ W1,
                                              __half* __restrict__ Wpk1,
                                              __half* __restrict__ Wpk2,
                                              __half* __restrict__ Wpk3,
                                              int* __restrict__ bcnt)
{
    const int idx = blockIdx.x * 256 + threadIdx.x;
    if (idx < NBUCK) bcnt[idx] = 0;
    if (idx < 24576) {                                  // GEMM1: 6 ks * 8 t
        const int i  = idx & 7;
        const int l  = (idx >> 3) & 63;
        const int tt = (idx >> 9) & 7;
        const int ks = idx >> 12;
        const int k   = ks * 32 + (l >> 4) * 8 + i;
        const int col = tt * 16 + (l & 15);
        const float v = (k < F_IN) ? Win[k * HID + col] : 0.0f;
        Wpk1[idx] = __float2half(v);
    } else if (idx < 40960) {                           // GEMM2: 4 ks * 8 t
        const int j  = idx - 24576;
        const int i  = j & 7;
        const int l  = (j >> 3) & 63;
        const int tt = (j >> 9) & 7;
        const int ks = j >> 12;
        const int k   = ks * 32 + (l >> 4) * 8 + i;
        const int col = tt * 16 + (l & 15);
        Wpk2[j] = __float2half(Wgat[k * HID + col]);
    } else {                                            // MLP W1: 4 ks * 4 t
        const int j  = idx - 40960;
        const int i  = j & 7;
        const int l  = (j >> 3) & 63;
        const int tt = (j >> 9) & 3;
        const int ks = j >> 11;
        const int k   = ks * 32 + (l >> 4) * 8 + i;
        const int col = tt * 16 + (l & 15);
        Wpk3[j] = __float2half(W1[k * 64 + col]);
    }
}

// ---------------------------------------------------------------------------
// k_proj (R22, unchanged): 512 threads / 8 waves; wave = rowgroup(4) x
// colgroup(2), 4 col-tiles/wave; 25.6 KB LDS. C/D col=lane&15,
// row=(lane>>4)*4+reg (m89/m91). aS/aD from restaged fp16 hW in LDS.
// Tail: fused edge binning — dense per-(block,bucket) interm ranges.
// ---------------------------------------------------------------------------
__global__ __launch_bounds__(512) void k_proj(
    const float* __restrict__ x,
    const __half* __restrict__ Wpk1, const __half* __restrict__ Wpk2,
    const float* __restrict__ bin,
    const float* __restrict__ attS, const float* __restrict__ attD,
    __half* __restrict__ hWh, float* __restrict__ aS, float* __restrict__ aD,
    const int* __restrict__ ei, int* __restrict__ bcnt,
    int* __restrict__ interm)
{
    __shared__ __align__(16) __half sh[PROJ_ROWS * 200];   // 25600 B

    const int t    = threadIdx.x;
    const int row0 = blockIdx.x * PROJ_ROWS;
    const int w    = t >> 6;
    const int lane = t & 63;
    const int l15  = lane & 15;
    const int g    = lane >> 4;
    const int rg4  = w & 3;           // rowgroup
    const int cgr  = w >> 2;          // colgroup (0: cols 0-63, 1: 64-127)
    const int arow = rg4 * 16 + l15;

    for (int idx = t; idx < PROJ_ROWS * 100; idx += 512) {
        const int r   = idx / 100;
        const int kk2 = (idx - r * 100) * 2;
        float2 v = make_float2(0.f, 0.f);
        const int row = row0 + r;
        if (row < N && kk2 < F_IN)
            v = *(const float2*)&x[(size_t)row * F_IN + kk2];
        *(__half2*)&sh[r * 200 + kk2] = __float22half2_rn(v);
    }
    __syncthreads();

    f32x4 acc[4];
#pragma unroll
    for (int tt = 0; tt < 4; ++tt)
#pragma unroll
        for (int q = 0; q < 4; ++q) acc[tt][q] = 0.0f;

#pragma unroll
    for (int ks = 0; ks < 6; ++ks) {
        const half8 a = *(const half8*)&sh[arow * 200 + ks * 32 + g * 8];
        const half8* bp = (const half8*)&Wpk1[ks * 4096 + cgr * 2048 + lane * 8];
#pragma unroll
        for (int tt = 0; tt < 4; ++tt) {
            acc[tt] = __builtin_amdgcn_mfma_f32_16x16x32_f16(a, bp[tt * 64], acc[tt], 0, 0, 0);
        }
    }

    __syncthreads();

#pragma unroll
    for (int tt = 0; tt < 4; ++tt) {
        const int col = (cgr * 4 + tt) * 16 + l15;
        const float bv = bin[col];
#pragma unroll
        for (int rg = 0; rg < 4; ++rg) {
            const int r = rg4 * 16 + g * 4 + rg;
            sh[r * 136 + col] = __float2half(fmaxf(acc[tt][rg] + bv, 0.0f));
        }
    }
    __syncthreads();

#pragma unroll
    for (int tt = 0; tt < 4; ++tt)
#pragma unroll
        for (int q = 0; q < 4; ++q) acc[tt][q] = 0.0f;

#pragma unroll
    for (int ks = 0; ks < 4; ++ks) {
        const half8 a = *(const half8*)&sh[arow * 136 + ks * 32 + g * 8];
        const half8* bp = (const half8*)&Wpk2[ks * 4096 + cgr * 2048 + lane * 8];
#pragma unroll
        for (int tt = 0; tt < 4; ++tt) {
            acc[tt] = __builtin_amdgcn_mfma_f32_16x16x32_f16(a, bp[tt * 64], acc[tt], 0, 0, 0);
        }
    }

    __syncthreads();   // all waves done reading h-tile
#pragma unroll
    for (int tt = 0; tt < 4; ++tt) {
        const int col = (cgr * 4 + tt) * 16 + l15;
#pragma unroll
        for (int rg = 0; rg < 4; ++rg) {
            const int r = rg4 * 16 + g * 4 + rg;
            sh[r * 136 + col] = __float2half(acc[tt][rg]);
        }
    }
    __syncthreads();

    // ---- aS/aD from LDS hW (8 threads/row: 16 cols each; head = c8>>1) ----
    {
        const int r2   = t >> 3;        // 0..63
        const int c8   = t & 7;
        const int head = c8 >> 1;
        float ps = 0.0f, pd = 0.0f;
#pragma unroll
        for (int k2 = 0; k2 < 8; ++k2) {
            const int col = c8 * 16 + k2 * 2;
            const __half2 hv = *(const __half2*)&sh[r2 * 136 + col];
            const float v0 = __low2float(hv), v1 = __high2float(hv);
            ps = fmaf(v0, attS[col], fmaf(v1, attS[col + 1], ps));
            pd = fmaf(v0, attD[col], fmaf(v1, attD[col + 1], pd));
        }
        ps += __shfl_xor(ps, 1);
        pd += __shfl_xor(pd, 1);
        const int row = row0 + r2;
        if (!(c8 & 1) && row < N) {
            aS[row * 4 + head] = ps;
            aD[row * 4 + head] = pd;
        }
    }

    // ---- hW coalesced global store ----
    for (int idx = t; idx < PROJ_ROWS * 16; idx += 512) {
        const int r  = idx >> 4;
        const int c8 = idx & 15;
        const int row = row0 + r;
        if (row < N) {
            const uint4 v = *(const uint4*)&sh[r * 136 + c8 * 8];
            *(uint4*)&hWh[(size_t)row * HID + c8 * 8] = v;
        }
    }

    // ---- fused edge-binning tail (was k_binA) ----
    __syncthreads();                    // done reading sh; reuse as int scratch
    int* hist  = (int*)sh;              // [64]
    int* basep = hist + 64;             // [64]
    int* offp  = hist + 128;            // [64]
    if (t < NBUCK) hist[t] = 0;
    __syncthreads();

    const int e0 = blockIdx.x * EPB;
    int pk[2], bk[2];
#pragma unroll
    for (int j = 0; j < 2; ++j) {
        const int i = e0 + j * 512 + t;
        bk[j] = -1;
        if (i < E) {
            const int s = ei[i], d = ei[E + i];
            const int b = d >> 11;
            bk[j] = b;
            pk[j] = s | ((d & 2047) << 17);
            atomicAdd(&hist[b], 1);
        }
    }
    __syncthreads();
    if (t < NBUCK) { basep[t] = atomicAdd(&bcnt[t], hist[t]); offp[t] = 0; }
    __syncthreads();
#pragma unroll
    for (int j = 0; j < 2; ++j) {
        if (bk[j] >= 0) {
            const int p   = atomicAdd(&offp[bk[j]], 1);
            const int pos = basep[bk[j]] + p;
            if (pos < BCAP) interm[bk[j] * BCAP + pos] = pk[j];
        }
    }
}

// ---------------------------------------------------------------------------
// k_binB (R22, unchanged): 1024 threads, one wg per bucket.
// ---------------------------------------------------------------------------
__global__ __launch_bounds__(1024) void k_binB(const int* __restrict__ interm,
                                               const int* __restrict__ bcnt,
                                               int* __restrict__ rowstart,
                                               int* __restrict__ csr)
{
    __shared__ int cnt[2048];
    __shared__ int wsum[1024];
    __shared__ int sbase;
    const int t      = threadIdx.x;
    const int bucket = blockIdx.x;

    if (t < 64) {                       // exclusive prefix for OUR bucket
        int v = (t < NBUCK && t < bucket) ? min(bcnt[t], BCAP) : 0;
#pragma unroll
        for (int off = 32; off >= 1; off >>= 1) v += __shfl_xor(v, off);
        if (t == 0) sbase = v;
    }
    if (bucket == 0 && t == 0) rowstart[N] = E;
    for (int i = t; i < 2048; i += 1024) cnt[i] = 0;
    __syncthreads();

    const int total = min(bcnt[bucket], BCAP);
    const int beg   = bucket * BCAP;
    for (int i = beg + t; i < beg + total; i += 1024)
        atomicAdd(&cnt[interm[i] >> 17], 1);
    __syncthreads();

    const int l0 = cnt[t * 2], l1 = cnt[t * 2 + 1];
    const int s  = l0 + l1;
    wsum[t] = s;
    __syncthreads();
    for (int off = 1; off < 1024; off <<= 1) {
        const int v = (t >= off) ? wsum[t - off] : 0;
        __syncthreads();
        wsum[t] += v;
        __syncthreads();
    }
    int run = sbase + wsum[t] - s;
    {
        const int node = bucket * 2048 + t * 2;
        cnt[t * 2] = run;
        if (node < N) rowstart[node] = run;
        run += l0;
        cnt[t * 2 + 1] = run;
        if (node + 1 < N) rowstart[node + 1] = run;
    }
    __syncthreads();

    for (int i = beg + t; i < beg + total; i += 1024) {
        const int p   = interm[i];
        const int pos = atomicAdd(&cnt[p >> 17], 1);
        csr[pos] = p & 0x1FFFF;
    }
}

// ---------------------------------------------------------------------------
// K_agg R23: wave per node; batch-preload structure. Per 16-edge batch the
// lane grid becomes (head 4 x edge 16): ONE coalesced csr read, one aS
// gather, ONE exp wave-op for all 16 edges x 4 heads (was 16x redundant
// per-cg recompute), ss reduced from preload values (off the inner loop).
// Gather loop (slot 4 x cg 16): 2 shfl + independent-address hW load + 8
// fma per 4 edges — all batch addresses ready up-front -> 4+ loads in
// flight (was 1-2, dependent chain; R22 counters: 3.6/6.3 TB/s, VALU 52%).
// Self-loop folds in as edge index 0; invalid tail lanes read hW[n] with
// x=0 (safe, L1-merged).
// ---------------------------------------------------------------------------
__global__ __launch_bounds__(256) void k_agg(
    const int* __restrict__ rowstart, const int* __restrict__ csr,
    const float* __restrict__ aS, const float* __restrict__ aD,
    const __half* __restrict__ hWh, const float4* __restrict__ bgat4,
    __half* __restrict__ gout)
{
    const int t = threadIdx.x;
    const int w = t >> 6;
    const int n = blockIdx.x * 4 + w;
    const int lane = t & 63;
    const int slot = lane >> 4;      // gather: 4 edge slots
    const int cg   = lane & 15;      // gather: 16 col groups (8 cols each)
    const int head = cg >> 2;
    const int eh   = lane >> 4;      // preload: head 0..3
    const int ee   = lane & 15;      // preload: edge slot 0..15

    const int r0 = rowstart[n], r1 = rowstart[n + 1];
    const int deg = r1 - r0;
    const int cnt = deg + 1;         // +1: self-loop as edge 0

    const float adh_pre = aD[n * 4 + eh];

    float4 a0 = {0.f,0.f,0.f,0.f}, a1 = {0.f,0.f,0.f,0.f};
    float ssp = 0.0f;                // per-lane partial of sum(x), head = eh

    for (int b = 0; b * 16 < cnt; ++b) {
        // ---- preload: edge eidx = b*16+ee, head eh ----
        const int eidx = b * 16 + ee;
        int src = n;
        if (eidx >= 1 && eidx <= deg) src = csr[r0 + eidx - 1];
        float xv = 0.0f;
        if (eidx <= deg) xv = __expf(lrelu(aS[src * 4 + eh] + adh_pre));
        ssp += xv;

        // ---- gather: 4 edges per unrolled iter across slots ----
        const int rem = min(16, cnt - b * 16);
#pragma unroll 4
        for (int i = 0; i < 4; ++i) {
            if (i * 4 >= rem) break;
            const int k  = i * 4 + slot;              // edge within batch
            const int sk = __shfl(src, k);            // lane k (eh=0 group)
            const float xk = __shfl(xv, (head << 4) | k);
            const float4 q = *(const float4*)&hWh[(size_t)sk * HID + cg * 8];
            acc8h(q, xk, a0, a1);
        }
    }

    // ---- ss: reduce preload partials over the 16 edge-lanes per head ----
#pragma unroll
    for (int off = 1; off <= 8; off <<= 1) ssp += __shfl_xor(ssp, off);
    const float ss = __shfl(ssp, head << 4);          // this lane's head total

    // ---- reduce acc across the 4 slots (lane bits 4..5) ----
#pragma unroll
    for (int off = 16; off <= 32; off <<= 1) {
        a0.x += __shfl_xor(a0.x, off); a0.y += __shfl_xor(a0.y, off);
        a0.z += __shfl_xor(a0.z, off); a0.w += __shfl_xor(a0.w, off);
        a1.x += __shfl_xor(a1.x, off); a1.y += __shfl_xor(a1.y, off);
        a1.z += __shfl_xor(a1.z, off); a1.w += __shfl_xor(a1.w, off);
    }

    // slot-0 lanes own 8 cols each: normalize, +b_gat, fp16 store to gout
    if (slot == 0) {
        const float inv = 1.0f / (ss + 1e-16f);
        const float4 bg0 = bgat4[cg * 2 + 0];
        const float4 bg1 = bgat4[cg * 2 + 1];
        const __half2 h0 = __float22half2_rn(make_float2(a0.x*inv+bg0.x, a0.y*inv+bg0.y));
        const __half2 h1 = __float22half2_rn(make_float2(a0.z*inv+bg0.z, a0.w*inv+bg0.w));
        const __half2 h2 = __float22half2_rn(make_float2(a1.x*inv+bg1.x, a1.y*inv+bg1.y));
        const __half2 h3 = __float22half2_rn(make_float2(a1.z*inv+bg1.z, a1.w*inv+bg1.w));
        uint4 p;
        p.x = *(const unsigned*)&h0; p.y = *(const unsigned*)&h1;
        p.z = *(const unsigned*)&h2; p.w = *(const unsigned*)&h3;
        *(uint4*)&gout[(size_t)n * HID + cg * 8] = p;
    }
}

// ---------------------------------------------------------------------------
// k_mlp (R16, unchanged): MFMA MLP head.
// ---------------------------------------------------------------------------
__global__ __launch_bounds__(256) void k_mlp(
    const __half* __restrict__ gout, const __half* __restrict__ Wpk3,
    const float* __restrict__ b1, const float* __restrict__ W2,
    const float* __restrict__ b2, float2* __restrict__ out)
{
    const int t = threadIdx.x;
    const int w = t >> 6, lane = t & 63;
    const int l15 = lane & 15, g = lane >> 4;
    const int rowbase = blockIdx.x * 64 + w * 16;
    const int arow = rowbase + l15;
    const bool arok = (arow < N);

    f32x4 acc[4];
#pragma unroll
    for (int tt = 0; tt < 4; ++tt)
#pragma unroll
        for (int q = 0; q < 4; ++q) acc[tt][q] = 0.0f;

#pragma unroll
    for (int ks = 0; ks < 4; ++ks) {
        half8 a;
#pragma unroll
        for (int i = 0; i < 8; ++i) a[i] = (_Float16)0;
        if (arok) a = *(const half8*)&gout[(size_t)arow * HID + ks * 32 + g * 8];
        const half8* bp = (const half8*)&Wpk3[ks * 2048 + lane * 8];
#pragma unroll
        for (int tt = 0; tt < 4; ++tt)
            acc[tt] = __builtin_amdgcn_mfma_f32_16x16x32_f16(a, bp[tt * 64], acc[tt], 0, 0, 0);
    }

    float l0[4] = {0.f, 0.f, 0.f, 0.f}, l1[4] = {0.f, 0.f, 0.f, 0.f};
#pragma unroll
    for (int tt = 0; tt < 4; ++tt) {
        const int col = tt * 16 + l15;
        const float bv = b1[col];
        const float2 wv = *(const float2*)&W2[col * 2];
#pragma unroll
        for (int rg = 0; rg < 4; ++rg) {
            const float h2 = fmaxf(acc[tt][rg] + bv, 0.0f);
            l0[rg] = fmaf(h2, wv.x, l0[rg]);
            l1[rg] = fmaf(h2, wv.y, l1[rg]);
        }
    }
#pragma unroll
    for (int off = 1; off <= 8; off <<= 1) {
#pragma unroll
        for (int rg = 0; rg < 4; ++rg) {
            l0[rg] += __shfl_xor(l0[rg], off);
            l1[rg] += __shfl_xor(l1[rg], off);
        }
    }
    if (l15 == 0) {
        const float b20 = b2[0], b21 = b2[1];
#pragma unroll
        for (int rg = 0; rg < 4; ++rg) {
            const int row = rowbase + g * 4 + rg;
            if (row < N) out[row] = make_float2(l0[rg] + b20, l1[rg] + b21);
        }
    }
}

extern "C" void kernel_launch(void* const* d_in, const int* in_sizes, int n_in,
                              void* d_out, int out_size, void* d_ws, size_t ws_size,
                              hipStream_t stream) {
    const float* x     = (const float*)d_in[0];
    const int*   ei    = (const int*)d_in[1];
    const float* Win   = (const float*)d_in[2];
    const float* bin   = (const float*)d_in[3];
    const float* Wgat  = (const float*)d_in[4];
    const float* attS  = (const float*)d_in[5];
    const float* attD  = (const float*)d_in[6];
    const float* bgat  = (const float*)d_in[7];
    const float* W1    = (const float*)d_in[8];
    const float* b1    = (const float*)d_in[9];
    const float* W2    = (const float*)d_in[10];
    const float* b2    = (const float*)d_in[11];

    char* ws = (char*)d_ws;
    __half* hWh   = (__half*)(ws + HW_OFF);
    __half* gout  = (__half*)(ws + GOUT_OFF);
    int*   interm = (int*)(ws + GOUT_OFF);    // aliases gout; dead before k_agg
    float* aS     = (float*)(ws + ASRC_OFF);
    float* aD     = (float*)(ws + ADST_OFF);
    int*   row    = (int*)(ws + ROW_OFF);
    int*   bcnt   = (int*)(ws + BCNT_OFF);
    __half* Wpk1  = (__half*)(ws + WPK1_OFF);
    __half* Wpk2  = (__half*)(ws + WPK2_OFF);
    __half* Wpk3  = (__half*)(ws + WPK3_OFF);
    int*   csr    = (int*)(ws + CSR_OFF);

    k_prep<<<192, 256, 0, stream>>>(Win, Wgat, W1, Wpk1, Wpk2, Wpk3, bcnt);
    k_proj<<<PROJ_NB, 512, 0, stream>>>(x, Wpk1, Wpk2, bin, attS, attD,
                                        hWh, aS, aD, ei, bcnt, interm);
    k_binB<<<NBUCK, 1024, 0, stream>>>(interm, bcnt, row, csr);
    k_agg<<<N / 4, 256, 0, stream>>>(row, csr, aS, aD, hWh,
                                     (const float4*)bgat, gout);
    k_mlp<<<MLP_NB, 256, 0, stream>>>(gout, Wpk3, b1, W2, b2, (float2*)d_out);
}